// Round 5
// baseline (2116.392 us; speedup 1.0000x reference)
//
#include <hip/hip_runtime.h>
#include <hip/hip_bf16.h>
#include <math.h>

// SpectralGPT forward on MI355X. B=4 T=1024 C=768 NH=12 HS=64 NL=6 VOCAB=128.
// Round 5: (1) attention Q-tile 128 (2x MFMA per softmax chain / barrier pair,
// biggest tiles dispatched first); (2) templated GEMM tile 128x128 or 64x128
// (proj/ff2/head get 2x grid occupancy); (3) single merged convert kernel.
// GEMM keeps round-4 global_load_lds + double-buffer + XOR-swizzled LDS.

#define Bz 4
#define Tz 1024
#define Cz 768
#define NHz 12
#define HSz 64
#define NLz 6
#define VOCABz 128
#define NTOK (Bz * Tz)  // 4096

typedef __hip_bfloat16 bf16;
typedef __attribute__((ext_vector_type(8))) __bf16 bf16x8;
typedef __attribute__((ext_vector_type(4))) float f32x4;

#define MFMA16(a, b, c) __builtin_amdgcn_mfma_f32_16x16x32_bf16(a, b, c, 0, 0, 0)

__device__ __forceinline__ float bf2f(bf16 x) { return __bfloat162float(x); }
__device__ __forceinline__ bf16 f2bf(float x) { return __float2bfloat16(x); }
__device__ __forceinline__ float ldx(const void* p, size_t i, int f) {
  return f ? bf2f(((const bf16*)p)[i]) : ((const float*)p)[i];
}
__device__ __forceinline__ void async16(const bf16* g, bf16* l) {
  __builtin_amdgcn_global_load_lds(
      (const __attribute__((address_space(1))) unsigned int*)g,
      (__attribute__((address_space(3))) unsigned int*)l, 16, 0, 0);
}

// -------------------------------------------------------------- dtype detect
__global__ void detect_kernel(const void* g1, int* flag) {
  if (threadIdx.x == 0) {
    const unsigned short* p = (const unsigned short*)g1;
    int cnt = 0;
    for (int i = 0; i < 64; i++) cnt += (p[i] == 0x3F80u) ? 1 : 0;
    *flag = (cnt >= 60) ? 1 : 0;
  }
}

// ------------------------------------------------- merged convert -> bf16
#define NCONV 15
struct CPack {
  const void* s[NCONV];
  bf16* d[NCONV];
  int n[NCONV];
};
__global__ __launch_bounds__(256) void convert_all(CPack p, const int* __restrict__ flagp) {
  int f = *flagp;
  int stride = gridDim.x * 256;
#pragma unroll 1
  for (int t = 0; t < NCONV; t++) {
    int n = p.n[t];
    const void* src = p.s[t];
    bf16* dst = p.d[t];
    for (int i = blockIdx.x * 256 + threadIdx.x; i < n; i += stride)
      dst[i] = f ? ((const bf16*)src)[i] : f2bf(((const float*)src)[i]);
  }
}

// -------------------------------------------- tiled transpose (coalesced)
__global__ __launch_bounds__(256) void transpose_tiled(
    const void* __restrict__ src, bf16* __restrict__ dst, int R, int C,
    size_t s_mat, size_t d_base, size_t d_l, size_t d_h, int hmod,
    const int* __restrict__ flagp) {
  __shared__ bf16 t[64][65];
  int f = *flagp;
  int c0 = blockIdx.x * 64, r0 = blockIdx.y * 64;
  int z = blockIdx.z;
  size_t so = (size_t)z * s_mat;
  size_t dofs = d_base + (size_t)(z / hmod) * d_l + (size_t)(z % hmod) * d_h;
  int tr = threadIdx.x >> 2;
  int tc = (threadIdx.x & 3) * 16;
  size_t sbase = so + (size_t)(r0 + tr) * C + c0 + tc;
#pragma unroll
  for (int u = 0; u < 16; u++) t[tr][tc + u] = f2bf(ldx(src, sbase + u, f));
  __syncthreads();
  int wc = threadIdx.x >> 2;
  int wr = (threadIdx.x & 3) * 16;
  bf16* dp = dst + dofs + (size_t)(c0 + wc) * R + r0 + wr;
#pragma unroll
  for (int u = 0; u < 16; u++) dp[u] = t[wr + u][wc];
}

// ---------------------------------------------------------------- embedding
__global__ __launch_bounds__(256) void embed_kernel(
    const int* __restrict__ idx, const bf16* __restrict__ tok_emb,
    const bf16* __restrict__ pe_w, const bf16* __restrict__ pe_b,
    const bf16* __restrict__ vlut, float* __restrict__ x_res) {
  int row = blockIdx.x;
  int t = row % Tz;
  int tok = idx[row];
  float vl[10];
#pragma unroll
  for (int p = 0; p < 10; p++) vl[p] = bf2f(vlut[t * 10 + p]);
  for (int c = threadIdx.x; c < Cz; c += 256) {
    float acc = bf2f(tok_emb[(size_t)tok * Cz + c]) + bf2f(pe_b[c]);
#pragma unroll
    for (int p = 0; p < 10; p++) acc += vl[p] * bf2f(pe_w[p * Cz + c]);
    x_res[(size_t)row * Cz + c] = acc;
  }
}

// ---------------------------------------------------------------- layernorm
__global__ __launch_bounds__(256) void ln_kernel(
    const float* __restrict__ x, const bf16* __restrict__ g,
    const bf16* __restrict__ b, bf16* __restrict__ out) {
  __shared__ float r1[4], r2[4];
  int row = blockIdx.x, tid = threadIdx.x;
  const float* xr = x + (size_t)row * Cz;
  float v0 = xr[tid], v1 = xr[tid + 256], v2 = xr[tid + 512];
  float s1 = v0 + v1 + v2, s2 = v0 * v0 + v1 * v1 + v2 * v2;
#pragma unroll
  for (int off = 32; off > 0; off >>= 1) {
    s1 += __shfl_down(s1, off);
    s2 += __shfl_down(s2, off);
  }
  int lane = tid & 63, wid = tid >> 6;
  if (lane == 0) { r1[wid] = s1; r2[wid] = s2; }
  __syncthreads();
  s1 = r1[0] + r1[1] + r1[2] + r1[3];
  s2 = r2[0] + r2[1] + r2[2] + r2[3];
  float m = s1 * (1.0f / Cz);
  float var = s2 * (1.0f / Cz) - m * m;
  float inv = rsqrtf(var + 1e-5f);
  bf16* orow = out + (size_t)row * Cz;
  orow[tid] = f2bf((v0 - m) * inv * bf2f(g[tid]) + bf2f(b[tid]));
  orow[tid + 256] = f2bf((v1 - m) * inv * bf2f(g[tid + 256]) + bf2f(b[tid + 256]));
  orow[tid + 512] = f2bf((v2 - m) * inv * bf2f(g[tid + 512]) + bf2f(b[tid + 512]));
}

// ---------------------------------------------------------------- MFMA GEMM
// C[M,N] = A[M,K](bf16 rowmajor) x W(pre-transposed [N][K]) + bias
// Tile: (MT*32) x 128, BK=32. MT=4 -> 128x128, MT=2 -> 64x128.
// Double-buffered LDS via global_load_lds; XOR-swizzled layout:
// (row,colblk cb): rp=row>>1, pl=((row&1)<<2)|cb, pp=pl^(rp&7),
// byte = rp*128 + pp*16 -> conflict-free b128 reads, DMA-bijective.
template <int MT>
__global__ __launch_bounds__(256) void gemm_mfma(
    const bf16* __restrict__ A, const bf16* __restrict__ Wt,
    const bf16* __restrict__ bias, float* __restrict__ resid,
    void* __restrict__ out, int M, int N, int K, int mode,
    const int* __restrict__ flagp) {
  constexpr int TM = MT * 32;    // tile rows
  constexpr int API = MT / 2;    // A-staging insts per wave (2 or 1)
  __shared__ bf16 ldsA[2][TM * 32];
  __shared__ bf16 ldsB[2][4096];
  int tid = threadIdx.x;
  int lane = tid & 63, w = tid >> 6;
  int wm = (w >> 1) * (MT * 16), wn = (w & 1) * 64;
  int q = lane >> 4, ln = lane & 15;
  int m0 = blockIdx.y * TM, n0 = blockIdx.x * 128;

  const bf16* gA[API];
  const bf16* gB[2];
#pragma unroll
  for (int p = 0; p < API; p++) {
    int o = w * (API * 1024) + p * 1024 + lane * 16;
    int rp = o >> 7, pp = (o >> 4) & 7;
    int pl = pp ^ (rp & 7);
    int row = rp * 2 + (pl >> 2);
    int cb = pl & 3;
    gA[p] = A + (size_t)(m0 + row) * K + cb * 8;
  }
#pragma unroll
  for (int p = 0; p < 2; p++) {
    int o = w * 2048 + p * 1024 + lane * 16;
    int rp = o >> 7, pp = (o >> 4) & 7;
    int pl = pp ^ (rp & 7);
    int row = rp * 2 + (pl >> 2);
    int cb = pl & 3;
    gB[p] = Wt + (size_t)(n0 + row) * K + cb * 8;
  }
  int ppf = (((ln & 1) << 2) | q) ^ (ln >> 1);
  int aoff = wm * 32 + (ln >> 1) * 64 + ppf * 8;
  int boff = wn * 32 + (ln >> 1) * 64 + ppf * 8;

  f32x4 acc[MT][4] = {};
#pragma unroll
  for (int p = 0; p < API; p++)
    async16(gA[p], &ldsA[0][w * (API * 512) + p * 512]);
#pragma unroll
  for (int p = 0; p < 2; p++)
    async16(gB[p], &ldsB[0][w * 1024 + p * 512]);
  int cur = 0;
  for (int k0 = 0; k0 < K; k0 += 32) {
    __syncthreads();
    if (k0 + 32 < K) {
      int nxt = cur ^ 1;
#pragma unroll
      for (int p = 0; p < API; p++)
        async16(gA[p] + k0 + 32, &ldsA[nxt][w * (API * 512) + p * 512]);
#pragma unroll
      for (int p = 0; p < 2; p++)
        async16(gB[p] + k0 + 32, &ldsB[nxt][w * 1024 + p * 512]);
    }
    bf16x8 af[MT], bfr[4];
#pragma unroll
    for (int i = 0; i < MT; i++)
      af[i] = *(const bf16x8*)&ldsA[cur][aoff + i * 512];
#pragma unroll
    for (int j = 0; j < 4; j++)
      bfr[j] = *(const bf16x8*)&ldsB[cur][boff + j * 512];
#pragma unroll
    for (int i = 0; i < MT; i++)
#pragma unroll
      for (int j = 0; j < 4; j++)
        acc[i][j] = MFMA16(af[i], bfr[j], acc[i][j]);
    cur ^= 1;
  }
  int f = *flagp;
  float bj[4];
#pragma unroll
  for (int j = 0; j < 4; j++)
    bj[j] = bias ? bf2f(bias[n0 + wn + j * 16 + ln]) : 0.0f;
#pragma unroll
  for (int i = 0; i < MT; i++) {
#pragma unroll
    for (int j = 0; j < 4; j++) {
      int col = n0 + wn + j * 16 + ln;
#pragma unroll
      for (int r = 0; r < 4; r++) {
        int row = m0 + wm + i * 16 + q * 4 + r;
        float v = acc[i][j][r] + bj[j];
        size_t oi = (size_t)row * N + col;
        if (mode == 0) {
          ((bf16*)out)[oi] = f2bf(v);
        } else if (mode == 1) {
          ((bf16*)out)[oi] = f2bf(v * 0.5f * (1.0f + erff(v * 0.70710678118f)));
        } else if (mode == 2) {
          resid[oi] += v;
        } else {
          if (f) ((bf16*)out)[oi] = f2bf(v);
          else ((float*)out)[oi] = v;
        }
      }
    }
  }
}

// --------------------------------------------- V transpose: qkv -> Vt[bh][d][s]
#define ATS 72
__global__ __launch_bounds__(256) void transpose_v(
    const bf16* __restrict__ qkv, bf16* __restrict__ Vt) {
  __shared__ bf16 tile[64][ATS];
  int tid = threadIdx.x;
  int s0 = blockIdx.x * 64, bh = blockIdx.y;
  int b = bh / NHz, h = bh % NHz;
  int row = tid >> 2, c0 = (tid & 3) * 16;
  const bf16* src = qkv + ((size_t)(b * Tz + s0 + row)) * (3 * Cz) + 2 * Cz + h * HSz + c0;
  *(uint4*)&tile[row][c0] = *(const uint4*)src;
  *(uint4*)&tile[row][c0 + 8] = *(const uint4*)(src + 8);
  __syncthreads();
  int d = tid >> 2, sc0 = (tid & 3) * 16;
  unsigned int u[8];
#pragma unroll
  for (int m = 0; m < 8; m++) {
    unsigned int lo = *(const unsigned short*)&tile[sc0 + 2 * m][d];
    unsigned int hi = *(const unsigned short*)&tile[sc0 + 2 * m + 1][d];
    u[m] = lo | (hi << 16);
  }
  bf16* dst = Vt + ((size_t)bh * HSz + d) * Tz + s0 + sc0;
  ((uint4*)dst)[0] = make_uint4(u[0], u[1], u[2], u[3]);
  ((uint4*)dst)[1] = make_uint4(u[4], u[5], u[6], u[7]);
}

// ------------------------------------------------------- flash MFMA attention
// Q-tile 128 rows, K-tile 64. 4 waves; wave w owns rows [w*32, +32) (2 m-tiles).
// Biggest t-tiles dispatched first (qt = 7 - blockIdx.x).
__global__ __launch_bounds__(256) void attn_flash(
    const bf16* __restrict__ qkv, const bf16* __restrict__ Vt,
    const bf16* __restrict__ rbias, bf16* __restrict__ attn_out) {
  __shared__ bf16 Qs[128][ATS];
  __shared__ bf16 Ks[64][ATS];
  __shared__ bf16 Vs[64][ATS];
  __shared__ bf16 Ps[4][32][ATS];
  int tid = threadIdx.x;
  int lane = tid & 63, w = tid >> 6;
  int q = lane >> 4, ln = lane & 15;
  int qt = 7 - blockIdx.x;
  int t0 = qt * 128, bh = blockIdx.y;
  int b = bh / NHz, h = bh % NHz;
  const float scale = 0.03608439182435161f;  // C^-0.5 = 1/sqrt(768)
  int srow = tid >> 2, sc = (tid & 3) * 16;
  // stage Q tile (128 rows, two passes)
#pragma unroll
  for (int pass = 0; pass < 2; pass++) {
    int r = srow + pass * 64;
    const bf16* src = qkv + ((size_t)(b * Tz + t0 + r)) * (3 * Cz) + h * HSz + sc;
    *(uint4*)&Qs[r][sc] = *(const uint4*)src;
    *(uint4*)&Qs[r][sc + 8] = *(const uint4*)(src + 8);
  }
  float mrow[2][4], lrow[2][4];
  f32x4 Oacc[2][4] = {};
#pragma unroll
  for (int i = 0; i < 2; i++)
#pragma unroll
    for (int r = 0; r < 4; r++) { mrow[i][r] = -3.0e38f; lrow[i][r] = 0.0f; }
  int nk = 2 * qt + 2;

  for (int kt = 0; kt < nk; kt++) {
    int s0 = kt * 64;
    __syncthreads();
    {
      const bf16* ksrc = qkv + ((size_t)(b * Tz + s0 + srow)) * (3 * Cz) + Cz + h * HSz + sc;
      *(uint4*)&Ks[srow][sc] = *(const uint4*)ksrc;
      *(uint4*)&Ks[srow][sc + 8] = *(const uint4*)(ksrc + 8);
      const bf16* vsrc = Vt + ((size_t)bh * HSz + srow) * Tz + s0 + sc;
      *(uint4*)&Vs[srow][sc] = *(const uint4*)vsrc;
      *(uint4*)&Vs[srow][sc + 8] = *(const uint4*)(vsrc + 8);
    }
    __syncthreads();
    // ---- S = Q K^T  (wave: 2 m-tiles x 4 n-tiles x 2 k-slabs = 16 MFMAs)
    f32x4 sacc[2][4] = {};
#pragma unroll
    for (int ks = 0; ks < 64; ks += 32) {
      bf16x8 aq[2];
#pragma unroll
      for (int i = 0; i < 2; i++)
        aq[i] = *(const bf16x8*)&Qs[w * 32 + i * 16 + ln][ks + q * 8];
#pragma unroll
      for (int j = 0; j < 4; j++) {
        bf16x8 bk = *(const bf16x8*)&Ks[j * 16 + ln][ks + q * 8];
#pragma unroll
        for (int i = 0; i < 2; i++) sacc[i][j] = MFMA16(aq[i], bk, sacc[i][j]);
      }
    }
    // ---- mask + rbias
    float sval[2][4][4];
#pragma unroll
    for (int i = 0; i < 2; i++) {
#pragma unroll
      for (int j = 0; j < 4; j++) {
        int s_col = s0 + j * 16 + ln;
#pragma unroll
        for (int r = 0; r < 4; r++) {
          int t_row = t0 + w * 32 + i * 16 + q * 4 + r;
          float rb = bf2f(rbias[(size_t)t_row * Tz + s_col]);
          float v = sacc[i][j][r] * scale + rb;
          bool ok = (s_col <= t_row) && ((rb > 0.0f) || (s_col == t_row));
          sval[i][j][r] = ok ? v : -3.0e38f;
        }
      }
    }
    // ---- online softmax state update (per (i,r) row)
    float pf[2][4][4];
#pragma unroll
    for (int i = 0; i < 2; i++) {
      float rmax[4], psum[4];
#pragma unroll
      for (int r = 0; r < 4; r++)
        rmax[r] = fmaxf(fmaxf(sval[i][0][r], sval[i][1][r]),
                        fmaxf(sval[i][2][r], sval[i][3][r]));
#pragma unroll
      for (int msk = 8; msk >= 1; msk >>= 1)
#pragma unroll
        for (int r = 0; r < 4; r++)
          rmax[r] = fmaxf(rmax[r], __shfl_xor(rmax[r], msk));
      float nme[4], alpha[4];
#pragma unroll
      for (int r = 0; r < 4; r++) {
        float nm = fmaxf(mrow[i][r], rmax[r]);
        nme[r] = (nm < -1.0e37f) ? 0.0f : nm;
        alpha[r] = (mrow[i][r] < -1.0e37f) ? 0.0f : __expf(mrow[i][r] - nm);
        mrow[i][r] = nm;
        psum[r] = 0.0f;
      }
#pragma unroll
      for (int j = 0; j < 4; j++)
#pragma unroll
        for (int r = 0; r < 4; r++) {
          float p = __expf(sval[i][j][r] - nme[r]);
          pf[i][j][r] = p;
          psum[r] += p;
        }
#pragma unroll
      for (int msk = 8; msk >= 1; msk >>= 1)
#pragma unroll
        for (int r = 0; r < 4; r++) psum[r] += __shfl_xor(psum[r], msk);
#pragma unroll
      for (int r = 0; r < 4; r++) lrow[i][r] = alpha[r] * lrow[i][r] + psum[r];
#pragma unroll
      for (int jd = 0; jd < 4; jd++)
#pragma unroll
        for (int r = 0; r < 4; r++) Oacc[i][jd][r] *= alpha[r];
      // P -> wave-private LDS (D-layout -> A-layout)
#pragma unroll
      for (int j = 0; j < 4; j++)
#pragma unroll
        for (int r = 0; r < 4; r++)
          Ps[w][i * 16 + q * 4 + r][j * 16 + ln] = f2bf(pf[i][j][r]);
    }
    // ---- O += P V (2 m-tiles x 4 d-tiles x 2 k-slabs = 16 MFMAs)
#pragma unroll
    for (int ks = 0; ks < 64; ks += 32) {
      bf16x8 pa[2];
#pragma unroll
      for (int i = 0; i < 2; i++)
        pa[i] = *(const bf16x8*)&Ps[w][i * 16 + ln][ks + q * 8];
#pragma unroll
      for (int jd = 0; jd < 4; jd++) {
        bf16x8 vb = *(const bf16x8*)&Vs[jd * 16 + ln][ks + q * 8];
#pragma unroll
        for (int i = 0; i < 2; i++) Oacc[i][jd] = MFMA16(pa[i], vb, Oacc[i][jd]);
      }
    }
  }
#pragma unroll
  for (int i = 0; i < 2; i++)
#pragma unroll
    for (int r = 0; r < 4; r++) {
      float inv = 1.0f / lrow[i][r];
      int t_row = t0 + w * 32 + i * 16 + q * 4 + r;
#pragma unroll
      for (int jd = 0; jd < 4; jd++) {
        attn_out[(size_t)(b * Tz + t_row) * Cz + h * HSz + jd * 16 + ln] =
            f2bf(Oacc[i][jd][r] * inv);
      }
    }
}

// ---------------------------------------------------------------- launcher
extern "C" void kernel_launch(void* const* d_in, const int* in_sizes, int n_in,
                              void* d_out, int out_size, void* d_ws, size_t ws_size,
                              hipStream_t stream) {
  const int* idx = (const int*)d_in[0];
  int p0 = 7;
  if (n_in == 23) p0 = 6;
  else if (in_sizes[6] != Tz * Tz) p0 = 6;

  const void* r_tok_emb = d_in[1];
  const void* r_pe_w = d_in[2];
  const void* r_pe_b = d_in[3];
  const void* r_vlut = d_in[4];
  const void* r_rbias = d_in[5];
  const void* r_ln1_g = d_in[p0 + 0];
  const void* r_ln1_b = d_in[p0 + 1];
  const void* r_qw = d_in[p0 + 2];
  const void* r_kw = d_in[p0 + 3];
  const void* r_vw = d_in[p0 + 4];
  const void* r_proj_w = d_in[p0 + 5];
  const void* r_proj_b = d_in[p0 + 6];
  const void* r_ln2_g = d_in[p0 + 7];
  const void* r_ln2_b = d_in[p0 + 8];
  const void* r_ff1_w = d_in[p0 + 9];
  const void* r_ff1_b = d_in[p0 + 10];
  const void* r_ff2_w = d_in[p0 + 11];
  const void* r_ff2_b = d_in[p0 + 12];
  const void* r_lnf_g = d_in[p0 + 13];
  const void* r_lnf_b = d_in[p0 + 14];
  const void* r_head_w = d_in[p0 + 15];
  const void* r_head_b = d_in[p0 + 16];

  char* wsp = (char*)d_ws;
  auto alloc = [&](size_t bytes) {
    char* p = wsp;
    wsp += (bytes + 255) & ~(size_t)255;
    return (void*)p;
  };
  int* flag = (int*)alloc(256);
  float* x_res = (float*)alloc((size_t)NTOK * Cz * 4);
  bf16* h = (bf16*)alloc((size_t)NTOK * Cz * 2);
  bf16* qkv = (bf16*)alloc((size_t)NTOK * 3 * Cz * 2);
  bf16* attn = (bf16*)alloc((size_t)NTOK * Cz * 2);
  bf16* ffm = (bf16*)alloc((size_t)NTOK * 4 * Cz * 2);
  bf16* Vt = (bf16*)alloc((size_t)Bz * NHz * HSz * Tz * 2);
  bf16* wqkv_t = (bf16*)alloc((size_t)NLz * 3 * Cz * Cz * 2);
  bf16* proj_t = (bf16*)alloc((size_t)NLz * Cz * Cz * 2);
  bf16* ff1_t = (bf16*)alloc((size_t)NLz * 4 * Cz * Cz * 2);
  bf16* ff2_t = (bf16*)alloc((size_t)NLz * 4 * Cz * Cz * 2);
  bf16* head_t = (bf16*)alloc((size_t)VOCABz * Cz * 2);
  bf16* tok_emb = (bf16*)alloc((size_t)VOCABz * Cz * 2);
  bf16* pe_w = (bf16*)alloc(10 * Cz * 2);
  bf16* pe_b = (bf16*)alloc(Cz * 2);
  bf16* vlut = (bf16*)alloc(Tz * 10 * 2);
  bf16* rbias = (bf16*)alloc((size_t)Tz * Tz * 2);
  bf16* ln1_g = (bf16*)alloc(NLz * Cz * 2);
  bf16* ln1_b = (bf16*)alloc(NLz * Cz * 2);
  bf16* proj_b = (bf16*)alloc(NLz * Cz * 2);
  bf16* ln2_g = (bf16*)alloc(NLz * Cz * 2);
  bf16* ln2_b = (bf16*)alloc(NLz * Cz * 2);
  bf16* ff1_b = (bf16*)alloc(NLz * 4 * Cz * 2);
  bf16* ff2_b = (bf16*)alloc(NLz * Cz * 2);
  bf16* lnf_g = (bf16*)alloc(Cz * 2);
  bf16* lnf_b = (bf16*)alloc(Cz * 2);
  bf16* head_b = (bf16*)alloc(VOCABz * 2);

  detect_kernel<<<1, 64, 0, stream>>>(r_ln1_g, flag);

  CPack cp;
  const void* csrc[NCONV] = {r_tok_emb, r_pe_w, r_pe_b, r_vlut, r_rbias,
                             r_ln1_g, r_ln1_b, r_proj_b, r_ln2_g, r_ln2_b,
                             r_ff1_b, r_ff2_b, r_lnf_g, r_lnf_b, r_head_b};
  bf16* cdst[NCONV] = {tok_emb, pe_w, pe_b, vlut, rbias,
                       ln1_g, ln1_b, proj_b, ln2_g, ln2_b,
                       ff1_b, ff2_b, lnf_g, lnf_b, head_b};
  int cn[NCONV] = {VOCABz * Cz, 10 * Cz, Cz, Tz * 10, Tz * Tz,
                   NLz * Cz, NLz * Cz, NLz * Cz, NLz * Cz, NLz * Cz,
                   NLz * 4 * Cz, NLz * Cz, Cz, Cz, VOCABz};
  for (int i = 0; i < NCONV; i++) { cp.s[i] = csrc[i]; cp.d[i] = cdst[i]; cp.n[i] = cn[i]; }
  convert_all<<<1024, 256, 0, stream>>>(cp, flag);

  for (int g = 0; g < 3; g++) {
    const void* src = (g == 0) ? r_qw : (g == 1) ? r_kw : r_vw;
    transpose_tiled<<<dim3(1, Cz / 64, NLz * NHz), 256, 0, stream>>>(
        src, wqkv_t, Cz, HSz, (size_t)Cz * HSz,
        (size_t)g * Cz * Cz, (size_t)3 * Cz * Cz, (size_t)HSz * Cz, NHz, flag);
  }
  transpose_tiled<<<dim3(Cz / 64, Cz / 64, NLz), 256, 0, stream>>>(
      r_proj_w, proj_t, Cz, Cz, (size_t)Cz * Cz, 0, (size_t)Cz * Cz, 0, 1, flag);
  transpose_tiled<<<dim3(4 * Cz / 64, Cz / 64, NLz), 256, 0, stream>>>(
      r_ff1_w, ff1_t, Cz, 4 * Cz, (size_t)4 * Cz * Cz, 0, (size_t)4 * Cz * Cz, 0, 1, flag);
  transpose_tiled<<<dim3(Cz / 64, 4 * Cz / 64, NLz), 256, 0, stream>>>(
      r_ff2_w, ff2_t, 4 * Cz, Cz, (size_t)4 * Cz * Cz, 0, (size_t)4 * Cz * Cz, 0, 1, flag);
  transpose_tiled<<<dim3(VOCABz / 64, Cz / 64, 1), 256, 0, stream>>>(
      r_head_w, head_t, Cz, VOCABz, 0, 0, 0, 0, 1, flag);

  embed_kernel<<<NTOK, 256, 0, stream>>>(idx, tok_emb, pe_w, pe_b, vlut, x_res);

  for (int l = 0; l < NLz; l++) {
    ln_kernel<<<NTOK, 256, 0, stream>>>(x_res, ln1_g + l * Cz, ln1_b + l * Cz, h);
    gemm_mfma<4><<<dim3(3 * Cz / 128, NTOK / 128), 256, 0, stream>>>(
        h, wqkv_t + (size_t)l * 3 * Cz * Cz, nullptr, nullptr, qkv,
        NTOK, 3 * Cz, Cz, 0, flag);
    transpose_v<<<dim3(Tz / 64, Bz * NHz), 256, 0, stream>>>(qkv, Vt);
    attn_flash<<<dim3(Tz / 128, Bz * NHz), 256, 0, stream>>>(qkv, Vt, rbias, attn);
    gemm_mfma<2><<<dim3(Cz / 128, NTOK / 64), 256, 0, stream>>>(
        attn, proj_t + (size_t)l * Cz * Cz, proj_b + l * Cz, x_res, nullptr,
        NTOK, Cz, Cz, 2, flag);
    ln_kernel<<<NTOK, 256, 0, stream>>>(x_res, ln2_g + l * Cz, ln2_b + l * Cz, h);
    gemm_mfma<4><<<dim3(4 * Cz / 128, NTOK / 128), 256, 0, stream>>>(
        h, ff1_t + (size_t)l * 4 * Cz * Cz, ff1_b + (size_t)l * 4 * Cz, nullptr,
        ffm, NTOK, 4 * Cz, Cz, 1, flag);
    gemm_mfma<2><<<dim3(Cz / 128, NTOK / 64), 256, 0, stream>>>(
        ffm, ff2_t + (size_t)l * 4 * Cz * Cz, ff2_b + l * Cz, x_res, nullptr,
        NTOK, Cz, 4 * Cz, 2, flag);
  }
  ln_kernel<<<NTOK, 256, 0, stream>>>(x_res, lnf_g, lnf_b, h);
  gemm_mfma<2><<<dim3(VOCABz / 128, NTOK / 64), 256, 0, stream>>>(
      h, head_t, head_b, nullptr, d_out, NTOK, VOCABz, Cz, 3, flag);
}

// Round 6
// 1814.943 us; speedup vs baseline: 1.1661x; 1.1661x over previous
//
#include <hip/hip_runtime.h>
#include <hip/hip_bf16.h>
#include <math.h>

// SpectralGPT forward on MI355X. B=4 T=1024 C=768 NH=12 HS=64 NL=6 VOCAB=128.
// Round 6: attention reverted to 64-row Q-tile (4 blocks/CU) + register
// prefetch of next K/V tile during compute (hides global latency behind the
// softmax chain) + biggest-first dispatch. Wave-per-row layernorm (no LDS).
// GEMM: round-5 MT-templated global_load_lds double-buffered swizzled kernel.

#define Bz 4
#define Tz 1024
#define Cz 768
#define NHz 12
#define HSz 64
#define NLz 6
#define VOCABz 128
#define NTOK (Bz * Tz)  // 4096

typedef __hip_bfloat16 bf16;
typedef __attribute__((ext_vector_type(8))) __bf16 bf16x8;
typedef __attribute__((ext_vector_type(4))) float f32x4;

#define MFMA16(a, b, c) __builtin_amdgcn_mfma_f32_16x16x32_bf16(a, b, c, 0, 0, 0)

__device__ __forceinline__ float bf2f(bf16 x) { return __bfloat162float(x); }
__device__ __forceinline__ bf16 f2bf(float x) { return __float2bfloat16(x); }
__device__ __forceinline__ float ldx(const void* p, size_t i, int f) {
  return f ? bf2f(((const bf16*)p)[i]) : ((const float*)p)[i];
}
__device__ __forceinline__ void async16(const bf16* g, bf16* l) {
  __builtin_amdgcn_global_load_lds(
      (const __attribute__((address_space(1))) unsigned int*)g,
      (__attribute__((address_space(3))) unsigned int*)l, 16, 0, 0);
}

// -------------------------------------------------------------- dtype detect
__global__ void detect_kernel(const void* g1, int* flag) {
  if (threadIdx.x == 0) {
    const unsigned short* p = (const unsigned short*)g1;
    int cnt = 0;
    for (int i = 0; i < 64; i++) cnt += (p[i] == 0x3F80u) ? 1 : 0;
    *flag = (cnt >= 60) ? 1 : 0;
  }
}

// ------------------------------------------------- merged convert -> bf16
#define NCONV 15
struct CPack {
  const void* s[NCONV];
  bf16* d[NCONV];
  int n[NCONV];
};
__global__ __launch_bounds__(256) void convert_all(CPack p, const int* __restrict__ flagp) {
  int f = *flagp;
  int stride = gridDim.x * 256;
#pragma unroll 1
  for (int t = 0; t < NCONV; t++) {
    int n = p.n[t];
    const void* src = p.s[t];
    bf16* dst = p.d[t];
    for (int i = blockIdx.x * 256 + threadIdx.x; i < n; i += stride)
      dst[i] = f ? ((const bf16*)src)[i] : f2bf(((const float*)src)[i]);
  }
}

// -------------------------------------------- tiled transpose (coalesced)
__global__ __launch_bounds__(256) void transpose_tiled(
    const void* __restrict__ src, bf16* __restrict__ dst, int R, int C,
    size_t s_mat, size_t d_base, size_t d_l, size_t d_h, int hmod,
    const int* __restrict__ flagp) {
  __shared__ bf16 t[64][65];
  int f = *flagp;
  int c0 = blockIdx.x * 64, r0 = blockIdx.y * 64;
  int z = blockIdx.z;
  size_t so = (size_t)z * s_mat;
  size_t dofs = d_base + (size_t)(z / hmod) * d_l + (size_t)(z % hmod) * d_h;
  int tr = threadIdx.x >> 2;
  int tc = (threadIdx.x & 3) * 16;
  size_t sbase = so + (size_t)(r0 + tr) * C + c0 + tc;
#pragma unroll
  for (int u = 0; u < 16; u++) t[tr][tc + u] = f2bf(ldx(src, sbase + u, f));
  __syncthreads();
  int wc = threadIdx.x >> 2;
  int wr = (threadIdx.x & 3) * 16;
  bf16* dp = dst + dofs + (size_t)(c0 + wc) * R + r0 + wr;
#pragma unroll
  for (int u = 0; u < 16; u++) dp[u] = t[wr + u][wc];
}

// ---------------------------------------------------------------- embedding
__global__ __launch_bounds__(256) void embed_kernel(
    const int* __restrict__ idx, const bf16* __restrict__ tok_emb,
    const bf16* __restrict__ pe_w, const bf16* __restrict__ pe_b,
    const bf16* __restrict__ vlut, float* __restrict__ x_res) {
  int row = blockIdx.x;
  int t = row % Tz;
  int tok = idx[row];
  float vl[10];
#pragma unroll
  for (int p = 0; p < 10; p++) vl[p] = bf2f(vlut[t * 10 + p]);
  for (int c = threadIdx.x; c < Cz; c += 256) {
    float acc = bf2f(tok_emb[(size_t)tok * Cz + c]) + bf2f(pe_b[c]);
#pragma unroll
    for (int p = 0; p < 10; p++) acc += vl[p] * bf2f(pe_w[p * Cz + c]);
    x_res[(size_t)row * Cz + c] = acc;
  }
}

// ------------------------------------------------- layernorm (wave per row)
__global__ __launch_bounds__(256) void ln_kernel(
    const float* __restrict__ x, const bf16* __restrict__ g,
    const bf16* __restrict__ b, bf16* __restrict__ out) {
  int w = threadIdx.x >> 6, lane = threadIdx.x & 63;
  int row = blockIdx.x * 4 + w;
  const float* xr = x + (size_t)row * Cz;
  float v[12];
  float s1 = 0.0f, s2 = 0.0f;
#pragma unroll
  for (int i = 0; i < 12; i++) {
    v[i] = xr[lane + i * 64];
    s1 += v[i];
    s2 += v[i] * v[i];
  }
#pragma unroll
  for (int off = 32; off >= 1; off >>= 1) {
    s1 += __shfl_xor(s1, off);
    s2 += __shfl_xor(s2, off);
  }
  float m = s1 * (1.0f / Cz);
  float var = s2 * (1.0f / Cz) - m * m;
  float inv = rsqrtf(var + 1e-5f);
  bf16* orow = out + (size_t)row * Cz;
#pragma unroll
  for (int i = 0; i < 12; i++) {
    int c = lane + i * 64;
    orow[c] = f2bf((v[i] - m) * inv * bf2f(g[c]) + bf2f(b[c]));
  }
}

// ---------------------------------------------------------------- MFMA GEMM
// C[M,N] = A[M,K](bf16 rowmajor) x W(pre-transposed [N][K]) + bias
// Tile: (MT*32) x 128, BK=32. MT=4 -> 128x128, MT=2 -> 64x128.
// Double-buffered LDS via global_load_lds; XOR-swizzled layout:
// (row,colblk cb): rp=row>>1, pl=((row&1)<<2)|cb, pp=pl^(rp&7),
// byte = rp*128 + pp*16 -> conflict-free b128 reads, DMA-bijective.
template <int MT>
__global__ __launch_bounds__(256) void gemm_mfma(
    const bf16* __restrict__ A, const bf16* __restrict__ Wt,
    const bf16* __restrict__ bias, float* __restrict__ resid,
    void* __restrict__ out, int M, int N, int K, int mode,
    const int* __restrict__ flagp) {
  constexpr int TM = MT * 32;
  constexpr int API = MT / 2;
  __shared__ bf16 ldsA[2][TM * 32];
  __shared__ bf16 ldsB[2][4096];
  int tid = threadIdx.x;
  int lane = tid & 63, w = tid >> 6;
  int wm = (w >> 1) * (MT * 16), wn = (w & 1) * 64;
  int q = lane >> 4, ln = lane & 15;
  int m0 = blockIdx.y * TM, n0 = blockIdx.x * 128;

  const bf16* gA[API];
  const bf16* gB[2];
#pragma unroll
  for (int p = 0; p < API; p++) {
    int o = w * (API * 1024) + p * 1024 + lane * 16;
    int rp = o >> 7, pp = (o >> 4) & 7;
    int pl = pp ^ (rp & 7);
    int row = rp * 2 + (pl >> 2);
    int cb = pl & 3;
    gA[p] = A + (size_t)(m0 + row) * K + cb * 8;
  }
#pragma unroll
  for (int p = 0; p < 2; p++) {
    int o = w * 2048 + p * 1024 + lane * 16;
    int rp = o >> 7, pp = (o >> 4) & 7;
    int pl = pp ^ (rp & 7);
    int row = rp * 2 + (pl >> 2);
    int cb = pl & 3;
    gB[p] = Wt + (size_t)(n0 + row) * K + cb * 8;
  }
  int ppf = (((ln & 1) << 2) | q) ^ (ln >> 1);
  int aoff = wm * 32 + (ln >> 1) * 64 + ppf * 8;
  int boff = wn * 32 + (ln >> 1) * 64 + ppf * 8;

  f32x4 acc[MT][4] = {};
#pragma unroll
  for (int p = 0; p < API; p++)
    async16(gA[p], &ldsA[0][w * (API * 512) + p * 512]);
#pragma unroll
  for (int p = 0; p < 2; p++)
    async16(gB[p], &ldsB[0][w * 1024 + p * 512]);
  int cur = 0;
  for (int k0 = 0; k0 < K; k0 += 32) {
    __syncthreads();
    if (k0 + 32 < K) {
      int nxt = cur ^ 1;
#pragma unroll
      for (int p = 0; p < API; p++)
        async16(gA[p] + k0 + 32, &ldsA[nxt][w * (API * 512) + p * 512]);
#pragma unroll
      for (int p = 0; p < 2; p++)
        async16(gB[p] + k0 + 32, &ldsB[nxt][w * 1024 + p * 512]);
    }
    bf16x8 af[MT], bfr[4];
#pragma unroll
    for (int i = 0; i < MT; i++)
      af[i] = *(const bf16x8*)&ldsA[cur][aoff + i * 512];
#pragma unroll
    for (int j = 0; j < 4; j++)
      bfr[j] = *(const bf16x8*)&ldsB[cur][boff + j * 512];
#pragma unroll
    for (int i = 0; i < MT; i++)
#pragma unroll
      for (int j = 0; j < 4; j++)
        acc[i][j] = MFMA16(af[i], bfr[j], acc[i][j]);
    cur ^= 1;
  }
  int f = *flagp;
  float bj[4];
#pragma unroll
  for (int j = 0; j < 4; j++)
    bj[j] = bias ? bf2f(bias[n0 + wn + j * 16 + ln]) : 0.0f;
#pragma unroll
  for (int i = 0; i < MT; i++) {
#pragma unroll
    for (int j = 0; j < 4; j++) {
      int col = n0 + wn + j * 16 + ln;
#pragma unroll
      for (int r = 0; r < 4; r++) {
        int row = m0 + wm + i * 16 + q * 4 + r;
        float v = acc[i][j][r] + bj[j];
        size_t oi = (size_t)row * N + col;
        if (mode == 0) {
          ((bf16*)out)[oi] = f2bf(v);
        } else if (mode == 1) {
          ((bf16*)out)[oi] = f2bf(v * 0.5f * (1.0f + erff(v * 0.70710678118f)));
        } else if (mode == 2) {
          resid[oi] += v;
        } else {
          if (f) ((bf16*)out)[oi] = f2bf(v);
          else ((float*)out)[oi] = v;
        }
      }
    }
  }
}

// --------------------------------------------- V transpose: qkv -> Vt[bh][d][s]
#define ATS 72
__global__ __launch_bounds__(256) void transpose_v(
    const bf16* __restrict__ qkv, bf16* __restrict__ Vt) {
  __shared__ bf16 tile[64][ATS];
  int tid = threadIdx.x;
  int s0 = blockIdx.x * 64, bh = blockIdx.y;
  int b = bh / NHz, h = bh % NHz;
  int row = tid >> 2, c0 = (tid & 3) * 16;
  const bf16* src = qkv + ((size_t)(b * Tz + s0 + row)) * (3 * Cz) + 2 * Cz + h * HSz + c0;
  *(uint4*)&tile[row][c0] = *(const uint4*)src;
  *(uint4*)&tile[row][c0 + 8] = *(const uint4*)(src + 8);
  __syncthreads();
  int d = tid >> 2, sc0 = (tid & 3) * 16;
  unsigned int u[8];
#pragma unroll
  for (int m = 0; m < 8; m++) {
    unsigned int lo = *(const unsigned short*)&tile[sc0 + 2 * m][d];
    unsigned int hi = *(const unsigned short*)&tile[sc0 + 2 * m + 1][d];
    u[m] = lo | (hi << 16);
  }
  bf16* dst = Vt + ((size_t)bh * HSz + d) * Tz + s0 + sc0;
  ((uint4*)dst)[0] = make_uint4(u[0], u[1], u[2], u[3]);
  ((uint4*)dst)[1] = make_uint4(u[4], u[5], u[6], u[7]);
}

// ------------------------------------------------------- flash MFMA attention
// 64-row Q-tile, 64-col K-tile, 4 waves (wave w owns rows [w*16,+16)).
// Register prefetch: next K/V tile's global loads issue right after barrier 2
// and complete during compute; barrier 1 drains them into LDS writes.
// Biggest tiles first: qt = 15 - blockIdx.x.
__global__ __launch_bounds__(256) void attn_flash(
    const bf16* __restrict__ qkv, const bf16* __restrict__ Vt,
    const bf16* __restrict__ rbias, bf16* __restrict__ attn_out) {
  __shared__ bf16 Qs[64][ATS];
  __shared__ bf16 Ks[64][ATS];
  __shared__ bf16 Vs[64][ATS];
  __shared__ bf16 Ps[4][16][ATS];
  int tid = threadIdx.x;
  int lane = tid & 63, w = tid >> 6;
  int q = lane >> 4, ln = lane & 15;
  int qt = (int)gridDim.x - 1 - (int)blockIdx.x;
  int t0 = qt * 64, bh = blockIdx.y;
  int b = bh / NHz, h = bh % NHz;
  const float scale = 0.03608439182435161f;  // C^-0.5 = 1/sqrt(768)
  int srow = tid >> 2, sc = (tid & 3) * 16;
  // stage Q tile
  {
    const bf16* src = qkv + ((size_t)(b * Tz + t0 + srow)) * (3 * Cz) + h * HSz + sc;
    *(uint4*)&Qs[srow][sc] = *(const uint4*)src;
    *(uint4*)&Qs[srow][sc + 8] = *(const uint4*)(src + 8);
  }
  float mrow[4], lrow[4];
  f32x4 Oacc[4] = {};
#pragma unroll
  for (int r = 0; r < 4; r++) { mrow[r] = -3.0e38f; lrow[r] = 0.0f; }
  int t_base = t0 + w * 16 + q * 4;
  int nk = qt + 1;

  const bf16* kcol = qkv + (size_t)b * Tz * (3 * Cz) + Cz + h * HSz + sc;
  const bf16* vrow = Vt + ((size_t)bh * HSz + srow) * Tz + sc;
  // prefetch tile 0
  uint4 ka, kb, va, vb2;
  {
    const bf16* kp = kcol + (size_t)srow * (3 * Cz);
    ka = *(const uint4*)kp;
    kb = *(const uint4*)(kp + 8);
    va = *(const uint4*)vrow;
    vb2 = *(const uint4*)(vrow + 8);
  }
  for (int kt = 0; kt < nk; kt++) {
    __syncthreads();  // all waves done reading previous Ks/Vs
    *(uint4*)&Ks[srow][sc] = ka;
    *(uint4*)&Ks[srow][sc + 8] = kb;
    *(uint4*)&Vs[srow][sc] = va;
    *(uint4*)&Vs[srow][sc + 8] = vb2;
    __syncthreads();  // tiles ready
    if (kt + 1 < nk) {
      const bf16* kp = kcol + (size_t)(((kt + 1) * 64) + srow) * (3 * Cz);
      ka = *(const uint4*)kp;
      kb = *(const uint4*)(kp + 8);
      const bf16* vp = vrow + (kt + 1) * 64;
      va = *(const uint4*)vp;
      vb2 = *(const uint4*)(vp + 8);
    }
    int s0 = kt * 64;
    // ---- S = Q K^T
    f32x4 sacc[4] = {};
#pragma unroll
    for (int ks = 0; ks < 64; ks += 32) {
      bf16x8 aq = *(const bf16x8*)&Qs[w * 16 + ln][ks + q * 8];
#pragma unroll
      for (int j = 0; j < 4; j++) {
        bf16x8 bk = *(const bf16x8*)&Ks[j * 16 + ln][ks + q * 8];
        sacc[j] = MFMA16(aq, bk, sacc[j]);
      }
    }
    // ---- mask + rbias
    float sval[4][4];
#pragma unroll
    for (int j = 0; j < 4; j++) {
      int s_col = s0 + j * 16 + ln;
#pragma unroll
      for (int r = 0; r < 4; r++) {
        int t_row = t_base + r;
        float rb = bf2f(rbias[(size_t)t_row * Tz + s_col]);
        float v = sacc[j][r] * scale + rb;
        bool ok = (s_col <= t_row) && ((rb > 0.0f) || (s_col == t_row));
        sval[j][r] = ok ? v : -3.0e38f;
      }
    }
    // ---- online softmax
    float rmax[4];
#pragma unroll
    for (int r = 0; r < 4; r++)
      rmax[r] = fmaxf(fmaxf(sval[0][r], sval[1][r]), fmaxf(sval[2][r], sval[3][r]));
#pragma unroll
    for (int msk = 8; msk >= 1; msk >>= 1)
#pragma unroll
      for (int r = 0; r < 4; r++)
        rmax[r] = fmaxf(rmax[r], __shfl_xor(rmax[r], msk));
    float nme[4], alpha[4];
#pragma unroll
    for (int r = 0; r < 4; r++) {
      float nm = fmaxf(mrow[r], rmax[r]);
      nme[r] = (nm < -1.0e37f) ? 0.0f : nm;
      alpha[r] = (mrow[r] < -1.0e37f) ? 0.0f : __expf(mrow[r] - nm);
      mrow[r] = nm;
    }
    float pf[4][4];
    float psum[4] = {0.f, 0.f, 0.f, 0.f};
#pragma unroll
    for (int j = 0; j < 4; j++)
#pragma unroll
      for (int r = 0; r < 4; r++) {
        float p = __expf(sval[j][r] - nme[r]);
        pf[j][r] = p;
        psum[r] += p;
      }
#pragma unroll
    for (int msk = 8; msk >= 1; msk >>= 1)
#pragma unroll
      for (int r = 0; r < 4; r++) psum[r] += __shfl_xor(psum[r], msk);
#pragma unroll
    for (int r = 0; r < 4; r++) lrow[r] = alpha[r] * lrow[r] + psum[r];
#pragma unroll
    for (int jd = 0; jd < 4; jd++)
#pragma unroll
      for (int r = 0; r < 4; r++) Oacc[jd][r] *= alpha[r];
    // ---- P -> LDS (D-layout -> A-layout), wave-private
#pragma unroll
    for (int j = 0; j < 4; j++)
#pragma unroll
      for (int r = 0; r < 4; r++)
        Ps[w][q * 4 + r][j * 16 + ln] = f2bf(pf[j][r]);
    // ---- O += P V
#pragma unroll
    for (int ks = 0; ks < 64; ks += 32) {
      bf16x8 pa = *(const bf16x8*)&Ps[w][ln][ks + q * 8];
#pragma unroll
      for (int jd = 0; jd < 4; jd++) {
        bf16x8 vb = *(const bf16x8*)&Vs[jd * 16 + ln][ks + q * 8];
        Oacc[jd] = MFMA16(pa, vb, Oacc[jd]);
      }
    }
  }
#pragma unroll
  for (int r = 0; r < 4; r++) {
    float inv = 1.0f / lrow[r];
    int t_row = t_base + r;
#pragma unroll
    for (int jd = 0; jd < 4; jd++) {
      attn_out[(size_t)(b * Tz + t_row) * Cz + h * HSz + jd * 16 + ln] =
          f2bf(Oacc[jd][r] * inv);
    }
  }
}

// ---------------------------------------------------------------- launcher
extern "C" void kernel_launch(void* const* d_in, const int* in_sizes, int n_in,
                              void* d_out, int out_size, void* d_ws, size_t ws_size,
                              hipStream_t stream) {
  const int* idx = (const int*)d_in[0];
  int p0 = 7;
  if (n_in == 23) p0 = 6;
  else if (in_sizes[6] != Tz * Tz) p0 = 6;

  const void* r_tok_emb = d_in[1];
  const void* r_pe_w = d_in[2];
  const void* r_pe_b = d_in[3];
  const void* r_vlut = d_in[4];
  const void* r_rbias = d_in[5];
  const void* r_ln1_g = d_in[p0 + 0];
  const void* r_ln1_b = d_in[p0 + 1];
  const void* r_qw = d_in[p0 + 2];
  const void* r_kw = d_in[p0 + 3];
  const void* r_vw = d_in[p0 + 4];
  const void* r_proj_w = d_in[p0 + 5];
  const void* r_proj_b = d_in[p0 + 6];
  const void* r_ln2_g = d_in[p0 + 7];
  const void* r_ln2_b = d_in[p0 + 8];
  const void* r_ff1_w = d_in[p0 + 9];
  const void* r_ff1_b = d_in[p0 + 10];
  const void* r_ff2_w = d_in[p0 + 11];
  const void* r_ff2_b = d_in[p0 + 12];
  const void* r_lnf_g = d_in[p0 + 13];
  const void* r_lnf_b = d_in[p0 + 14];
  const void* r_head_w = d_in[p0 + 15];
  const void* r_head_b = d_in[p0 + 16];

  char* wsp = (char*)d_ws;
  auto alloc = [&](size_t bytes) {
    char* p = wsp;
    wsp += (bytes + 255) & ~(size_t)255;
    return (void*)p;
  };
  int* flag = (int*)alloc(256);
  float* x_res = (float*)alloc((size_t)NTOK * Cz * 4);
  bf16* h = (bf16*)alloc((size_t)NTOK * Cz * 2);
  bf16* qkv = (bf16*)alloc((size_t)NTOK * 3 * Cz * 2);
  bf16* attn = (bf16*)alloc((size_t)NTOK * Cz * 2);
  bf16* ffm = (bf16*)alloc((size_t)NTOK * 4 * Cz * 2);
  bf16* Vt = (bf16*)alloc((size_t)Bz * NHz * HSz * Tz * 2);
  bf16* wqkv_t = (bf16*)alloc((size_t)NLz * 3 * Cz * Cz * 2);
  bf16* proj_t = (bf16*)alloc((size_t)NLz * Cz * Cz * 2);
  bf16* ff1_t = (bf16*)alloc((size_t)NLz * 4 * Cz * Cz * 2);
  bf16* ff2_t = (bf16*)alloc((size_t)NLz * 4 * Cz * Cz * 2);
  bf16* head_t = (bf16*)alloc((size_t)VOCABz * Cz * 2);
  bf16* tok_emb = (bf16*)alloc((size_t)VOCABz * Cz * 2);
  bf16* pe_w = (bf16*)alloc(10 * Cz * 2);
  bf16* pe_b = (bf16*)alloc(Cz * 2);
  bf16* vlut = (bf16*)alloc(Tz * 10 * 2);
  bf16* rbias = (bf16*)alloc((size_t)Tz * Tz * 2);
  bf16* ln1_g = (bf16*)alloc(NLz * Cz * 2);
  bf16* ln1_b = (bf16*)alloc(NLz * Cz * 2);
  bf16* proj_b = (bf16*)alloc(NLz * Cz * 2);
  bf16* ln2_g = (bf16*)alloc(NLz * Cz * 2);
  bf16* ln2_b = (bf16*)alloc(NLz * Cz * 2);
  bf16* ff1_b = (bf16*)alloc(NLz * 4 * Cz * 2);
  bf16* ff2_b = (bf16*)alloc(NLz * Cz * 2);
  bf16* lnf_g = (bf16*)alloc(Cz * 2);
  bf16* lnf_b = (bf16*)alloc(Cz * 2);
  bf16* head_b = (bf16*)alloc(VOCABz * 2);

  detect_kernel<<<1, 64, 0, stream>>>(r_ln1_g, flag);

  CPack cp;
  const void* csrc[NCONV] = {r_tok_emb, r_pe_w, r_pe_b, r_vlut, r_rbias,
                             r_ln1_g, r_ln1_b, r_proj_b, r_ln2_g, r_ln2_b,
                             r_ff1_b, r_ff2_b, r_lnf_g, r_lnf_b, r_head_b};
  bf16* cdst[NCONV] = {tok_emb, pe_w, pe_b, vlut, rbias,
                       ln1_g, ln1_b, proj_b, ln2_g, ln2_b,
                       ff1_b, ff2_b, lnf_g, lnf_b, head_b};
  int cn[NCONV] = {VOCABz * Cz, 10 * Cz, Cz, Tz * 10, Tz * Tz,
                   NLz * Cz, NLz * Cz, NLz * Cz, NLz * Cz, NLz * Cz,
                   NLz * 4 * Cz, NLz * Cz, Cz, Cz, VOCABz};
  for (int i = 0; i < NCONV; i++) { cp.s[i] = csrc[i]; cp.d[i] = cdst[i]; cp.n[i] = cn[i]; }
  convert_all<<<1024, 256, 0, stream>>>(cp, flag);

  for (int g = 0; g < 3; g++) {
    const void* src = (g == 0) ? r_qw : (g == 1) ? r_kw : r_vw;
    transpose_tiled<<<dim3(1, Cz / 64, NLz * NHz), 256, 0, stream>>>(
        src, wqkv_t, Cz, HSz, (size_t)Cz * HSz,
        (size_t)g * Cz * Cz, (size_t)3 * Cz * Cz, (size_t)HSz * Cz, NHz, flag);
  }
  transpose_tiled<<<dim3(Cz / 64, Cz / 64, NLz), 256, 0, stream>>>(
      r_proj_w, proj_t, Cz, Cz, (size_t)Cz * Cz, 0, (size_t)Cz * Cz, 0, 1, flag);
  transpose_tiled<<<dim3(4 * Cz / 64, Cz / 64, NLz), 256, 0, stream>>>(
      r_ff1_w, ff1_t, Cz, 4 * Cz, (size_t)4 * Cz * Cz, 0, (size_t)4 * Cz * Cz, 0, 1, flag);
  transpose_tiled<<<dim3(Cz / 64, 4 * Cz / 64, NLz), 256, 0, stream>>>(
      r_ff2_w, ff2_t, 4 * Cz, Cz, (size_t)4 * Cz * Cz, 0, (size_t)4 * Cz * Cz, 0, 1, flag);
  transpose_tiled<<<dim3(VOCABz / 64, Cz / 64, 1), 256, 0, stream>>>(
      r_head_w, head_t, Cz, VOCABz, 0, 0, 0, 0, 1, flag);

  embed_kernel<<<NTOK, 256, 0, stream>>>(idx, tok_emb, pe_w, pe_b, vlut, x_res);

  for (int l = 0; l < NLz; l++) {
    ln_kernel<<<NTOK / 4, 256, 0, stream>>>(x_res, ln1_g + l * Cz, ln1_b + l * Cz, h);
    gemm_mfma<4><<<dim3(3 * Cz / 128, NTOK / 128), 256, 0, stream>>>(
        h, wqkv_t + (size_t)l * 3 * Cz * Cz, nullptr, nullptr, qkv,
        NTOK, 3 * Cz, Cz, 0, flag);
    transpose_v<<<dim3(Tz / 64, Bz * NHz), 256, 0, stream>>>(qkv, Vt);
    attn_flash<<<dim3(Tz / 64, Bz * NHz), 256, 0, stream>>>(qkv, Vt, rbias, attn);
    gemm_mfma<2><<<dim3(Cz / 128, NTOK / 64), 256, 0, stream>>>(
        attn, proj_t + (size_t)l * Cz * Cz, proj_b + l * Cz, x_res, nullptr,
        NTOK, Cz, Cz, 2, flag);
    ln_kernel<<<NTOK / 4, 256, 0, stream>>>(x_res, ln2_g + l * Cz, ln2_b + l * Cz, h);
    gemm_mfma<4><<<dim3(4 * Cz / 128, NTOK / 128), 256, 0, stream>>>(
        h, ff1_t + (size_t)l * 4 * Cz * Cz, ff1_b + (size_t)l * 4 * Cz, nullptr,
        ffm, NTOK, 4 * Cz, Cz, 1, flag);
    gemm_mfma<2><<<dim3(Cz / 128, NTOK / 64), 256, 0, stream>>>(
        ffm, ff2_t + (size_t)l * 4 * Cz * Cz, ff2_b + l * Cz, x_res, nullptr,
        NTOK, Cz, 4 * Cz, 2, flag);
  }
  ln_kernel<<<NTOK / 4, 256, 0, stream>>>(x_res, lnf_g, lnf_b, h);
  gemm_mfma<2><<<dim3(VOCABz / 128, NTOK / 64), 256, 0, stream>>>(
      h, head_t, head_b, nullptr, d_out, NTOK, VOCABz, Cz, 3, flag);
}

// Round 7
// 1806.068 us; speedup vs baseline: 1.1718x; 1.0049x over previous
//
#include <hip/hip_runtime.h>
#include <hip/hip_bf16.h>
#include <math.h>

// SpectralGPT forward on MI355X. B=4 T=1024 C=768 NH=12 HS=64 NL=6 VOCAB=128.
// Round 7: (1) fused bias+mask matrix bm (bf16, precomputed) replaces per-
// element rbias load + mask logic in attention; (2) bm tile staged through LDS
// with the K/V register prefetch (global latency out of the softmax chain);
// (3) V-transpose fused into QKV GEMM epilogue (mode 5) - transpose_v removed.

#define Bz 4
#define Tz 1024
#define Cz 768
#define NHz 12
#define HSz 64
#define NLz 6
#define VOCABz 128
#define NTOK (Bz * Tz)  // 4096

typedef __hip_bfloat16 bf16;
typedef __attribute__((ext_vector_type(8))) __bf16 bf16x8;
typedef __attribute__((ext_vector_type(4))) float f32x4;

#define MFMA16(a, b, c) __builtin_amdgcn_mfma_f32_16x16x32_bf16(a, b, c, 0, 0, 0)

__device__ __forceinline__ float bf2f(bf16 x) { return __bfloat162float(x); }
__device__ __forceinline__ bf16 f2bf(float x) { return __float2bfloat16(x); }
__device__ __forceinline__ float ldx(const void* p, size_t i, int f) {
  return f ? bf2f(((const bf16*)p)[i]) : ((const float*)p)[i];
}
__device__ __forceinline__ void async16(const bf16* g, bf16* l) {
  __builtin_amdgcn_global_load_lds(
      (const __attribute__((address_space(1))) unsigned int*)g,
      (__attribute__((address_space(3))) unsigned int*)l, 16, 0, 0);
}

// -------------------------------------------------------------- dtype detect
__global__ void detect_kernel(const void* g1, int* flag) {
  if (threadIdx.x == 0) {
    const unsigned short* p = (const unsigned short*)g1;
    int cnt = 0;
    for (int i = 0; i < 64; i++) cnt += (p[i] == 0x3F80u) ? 1 : 0;
    *flag = (cnt >= 60) ? 1 : 0;
  }
}

// ------------------------------------------------- merged convert -> bf16
#define NCONV 15
struct CPack {
  const void* s[NCONV];
  bf16* d[NCONV];
  int n[NCONV];
};
__global__ __launch_bounds__(256) void convert_all(CPack p, const int* __restrict__ flagp) {
  int f = *flagp;
  int stride = gridDim.x * 256;
#pragma unroll 1
  for (int t = 0; t < NCONV; t++) {
    int n = p.n[t];
    const void* src = p.s[t];
    bf16* dst = p.d[t];
    for (int i = blockIdx.x * 256 + threadIdx.x; i < n; i += stride)
      dst[i] = f ? ((const bf16*)src)[i] : f2bf(((const float*)src)[i]);
  }
}

// -------------------------------------- fused bias+mask: bm = allowed?rb:-3e38
__global__ __launch_bounds__(256) void build_bm(
    const bf16* __restrict__ rbias, bf16* __restrict__ bm) {
  int i = blockIdx.x * 256 + threadIdx.x;  // 1M elements
  int t = i >> 10, s = i & 1023;
  bf16 rb16 = rbias[i];
  float rb = bf2f(rb16);
  bool ok = (s <= t) && ((rb > 0.0f) || (s == t));
  bm[i] = ok ? rb16 : f2bf(-3.0e38f);
}

// -------------------------------------------- tiled transpose (coalesced)
__global__ __launch_bounds__(256) void transpose_tiled(
    const void* __restrict__ src, bf16* __restrict__ dst, int R, int C,
    size_t s_mat, size_t d_base, size_t d_l, size_t d_h, int hmod,
    const int* __restrict__ flagp) {
  __shared__ bf16 t[64][65];
  int f = *flagp;
  int c0 = blockIdx.x * 64, r0 = blockIdx.y * 64;
  int z = blockIdx.z;
  size_t so = (size_t)z * s_mat;
  size_t dofs = d_base + (size_t)(z / hmod) * d_l + (size_t)(z % hmod) * d_h;
  int tr = threadIdx.x >> 2;
  int tc = (threadIdx.x & 3) * 16;
  size_t sbase = so + (size_t)(r0 + tr) * C + c0 + tc;
#pragma unroll
  for (int u = 0; u < 16; u++) t[tr][tc + u] = f2bf(ldx(src, sbase + u, f));
  __syncthreads();
  int wc = threadIdx.x >> 2;
  int wr = (threadIdx.x & 3) * 16;
  bf16* dp = dst + dofs + (size_t)(c0 + wc) * R + r0 + wr;
#pragma unroll
  for (int u = 0; u < 16; u++) dp[u] = t[wr + u][wc];
}

// ---------------------------------------------------------------- embedding
__global__ __launch_bounds__(256) void embed_kernel(
    const int* __restrict__ idx, const bf16* __restrict__ tok_emb,
    const bf16* __restrict__ pe_w, const bf16* __restrict__ pe_b,
    const bf16* __restrict__ vlut, float* __restrict__ x_res) {
  int row = blockIdx.x;
  int t = row % Tz;
  int tok = idx[row];
  float vl[10];
#pragma unroll
  for (int p = 0; p < 10; p++) vl[p] = bf2f(vlut[t * 10 + p]);
  for (int c = threadIdx.x; c < Cz; c += 256) {
    float acc = bf2f(tok_emb[(size_t)tok * Cz + c]) + bf2f(pe_b[c]);
#pragma unroll
    for (int p = 0; p < 10; p++) acc += vl[p] * bf2f(pe_w[p * Cz + c]);
    x_res[(size_t)row * Cz + c] = acc;
  }
}

// ------------------------------------------------- layernorm (wave per row)
__global__ __launch_bounds__(256) void ln_kernel(
    const float* __restrict__ x, const bf16* __restrict__ g,
    const bf16* __restrict__ b, bf16* __restrict__ out) {
  int w = threadIdx.x >> 6, lane = threadIdx.x & 63;
  int row = blockIdx.x * 4 + w;
  const float* xr = x + (size_t)row * Cz;
  float v[12];
  float s1 = 0.0f, s2 = 0.0f;
#pragma unroll
  for (int i = 0; i < 12; i++) {
    v[i] = xr[lane + i * 64];
    s1 += v[i];
    s2 += v[i] * v[i];
  }
#pragma unroll
  for (int off = 32; off >= 1; off >>= 1) {
    s1 += __shfl_xor(s1, off);
    s2 += __shfl_xor(s2, off);
  }
  float m = s1 * (1.0f / Cz);
  float var = s2 * (1.0f / Cz) - m * m;
  float inv = rsqrtf(var + 1e-5f);
  bf16* orow = out + (size_t)row * Cz;
#pragma unroll
  for (int i = 0; i < 12; i++) {
    int c = lane + i * 64;
    orow[c] = f2bf((v[i] - m) * inv * bf2f(g[c]) + bf2f(b[c]));
  }
}

// ---------------------------------------------------------------- MFMA GEMM
// C[M,N] = A[M,K](bf16 rowmajor) x W(pre-transposed [N][K]) + bias
// Tile: (MT*32) x 128, BK=32. MT=4 -> 128x128, MT=2 -> 64x128.
// modes: 0 out=bf16  1 out=bf16(gelu)  2 resid+=  3 per-flag out
//        5 qkv: cols<1536 -> out(qkv); cols>=1536 -> Vt[bh][d][t] (via resid)
template <int MT>
__global__ __launch_bounds__(256) void gemm_mfma(
    const bf16* __restrict__ A, const bf16* __restrict__ Wt,
    const bf16* __restrict__ bias, float* __restrict__ resid,
    void* __restrict__ out, int M, int N, int K, int mode,
    const int* __restrict__ flagp) {
  constexpr int TM = MT * 32;
  constexpr int API = MT / 2;
  __shared__ bf16 ldsA[2][TM * 32];
  __shared__ bf16 ldsB[2][4096];
  int tid = threadIdx.x;
  int lane = tid & 63, w = tid >> 6;
  int wm = (w >> 1) * (MT * 16), wn = (w & 1) * 64;
  int q = lane >> 4, ln = lane & 15;
  int m0 = blockIdx.y * TM, n0 = blockIdx.x * 128;

  const bf16* gA[API];
  const bf16* gB[2];
#pragma unroll
  for (int p = 0; p < API; p++) {
    int o = w * (API * 1024) + p * 1024 + lane * 16;
    int rp = o >> 7, pp = (o >> 4) & 7;
    int pl = pp ^ (rp & 7);
    int row = rp * 2 + (pl >> 2);
    int cb = pl & 3;
    gA[p] = A + (size_t)(m0 + row) * K + cb * 8;
  }
#pragma unroll
  for (int p = 0; p < 2; p++) {
    int o = w * 2048 + p * 1024 + lane * 16;
    int rp = o >> 7, pp = (o >> 4) & 7;
    int pl = pp ^ (rp & 7);
    int row = rp * 2 + (pl >> 2);
    int cb = pl & 3;
    gB[p] = Wt + (size_t)(n0 + row) * K + cb * 8;
  }
  int ppf = (((ln & 1) << 2) | q) ^ (ln >> 1);
  int aoff = wm * 32 + (ln >> 1) * 64 + ppf * 8;
  int boff = wn * 32 + (ln >> 1) * 64 + ppf * 8;

  f32x4 acc[MT][4] = {};
#pragma unroll
  for (int p = 0; p < API; p++)
    async16(gA[p], &ldsA[0][w * (API * 512) + p * 512]);
#pragma unroll
  for (int p = 0; p < 2; p++)
    async16(gB[p], &ldsB[0][w * 1024 + p * 512]);
  int cur = 0;
  for (int k0 = 0; k0 < K; k0 += 32) {
    __syncthreads();
    if (k0 + 32 < K) {
      int nxt = cur ^ 1;
#pragma unroll
      for (int p = 0; p < API; p++)
        async16(gA[p] + k0 + 32, &ldsA[nxt][w * (API * 512) + p * 512]);
#pragma unroll
      for (int p = 0; p < 2; p++)
        async16(gB[p] + k0 + 32, &ldsB[nxt][w * 1024 + p * 512]);
    }
    bf16x8 af[MT], bfr[4];
#pragma unroll
    for (int i = 0; i < MT; i++)
      af[i] = *(const bf16x8*)&ldsA[cur][aoff + i * 512];
#pragma unroll
    for (int j = 0; j < 4; j++)
      bfr[j] = *(const bf16x8*)&ldsB[cur][boff + j * 512];
#pragma unroll
    for (int i = 0; i < MT; i++)
#pragma unroll
      for (int j = 0; j < 4; j++)
        acc[i][j] = MFMA16(af[i], bfr[j], acc[i][j]);
    cur ^= 1;
  }
  int f = *flagp;
  float bj[4];
#pragma unroll
  for (int j = 0; j < 4; j++)
    bj[j] = bias ? bf2f(bias[n0 + wn + j * 16 + ln]) : 0.0f;
#pragma unroll
  for (int i = 0; i < MT; i++) {
#pragma unroll
    for (int j = 0; j < 4; j++) {
      int col = n0 + wn + j * 16 + ln;
#pragma unroll
      for (int r = 0; r < 4; r++) {
        int row = m0 + wm + i * 16 + q * 4 + r;
        float v = acc[i][j][r] + bj[j];
        size_t oi = (size_t)row * N + col;
        if (mode == 0) {
          ((bf16*)out)[oi] = f2bf(v);
        } else if (mode == 1) {
          ((bf16*)out)[oi] = f2bf(v * 0.5f * (1.0f + erff(v * 0.70710678118f)));
        } else if (mode == 2) {
          resid[oi] += v;
        } else if (mode == 5) {
          if (col < 2 * Cz) {
            ((bf16*)out)[oi] = f2bf(v);
          } else {
            int nn = col - 2 * Cz;
            int hh = nn >> 6, dd = nn & 63;
            int bb = row >> 10, tt = row & 1023;
            ((bf16*)resid)[(((size_t)(bb * NHz + hh)) * HSz + dd) * Tz + tt] = f2bf(v);
          }
        } else {
          if (f) ((bf16*)out)[oi] = f2bf(v);
          else ((float*)out)[oi] = v;
        }
      }
    }
  }
}

// ------------------------------------------------------- flash MFMA attention
// 64-row Q-tile, 64-col K-tile, 4 waves (wave w owns rows [w*16,+16)).
// K/V/bm tiles register-prefetched during compute, LDS-written at barrier.
// bm = precomputed allowed?rbias:-3e38 -> chain is LDS-read + fma only.
#define ATS 72
__global__ __launch_bounds__(256) void attn_flash(
    const bf16* __restrict__ qkv, const bf16* __restrict__ Vt,
    const bf16* __restrict__ bm, bf16* __restrict__ attn_out) {
  __shared__ bf16 Qs[64][ATS];
  __shared__ bf16 Ks[64][ATS];
  __shared__ bf16 Vs[64][ATS];
  __shared__ bf16 Bs[64][ATS];
  __shared__ bf16 Ps[4][16][ATS];
  int tid = threadIdx.x;
  int lane = tid & 63, w = tid >> 6;
  int q = lane >> 4, ln = lane & 15;
  int qt = (int)gridDim.x - 1 - (int)blockIdx.x;
  int t0 = qt * 64, bh = blockIdx.y;
  int b = bh / NHz, h = bh % NHz;
  const float scale = 0.03608439182435161f;  // C^-0.5 = 1/sqrt(768)
  int srow = tid >> 2, sc = (tid & 3) * 16;
  {
    const bf16* src = qkv + ((size_t)(b * Tz + t0 + srow)) * (3 * Cz) + h * HSz + sc;
    *(uint4*)&Qs[srow][sc] = *(const uint4*)src;
    *(uint4*)&Qs[srow][sc + 8] = *(const uint4*)(src + 8);
  }
  float mrow[4], lrow[4];
  f32x4 Oacc[4] = {};
#pragma unroll
  for (int r = 0; r < 4; r++) { mrow[r] = -3.0e38f; lrow[r] = 0.0f; }
  int t_base = t0 + w * 16 + q * 4;
  int nk = qt + 1;

  const bf16* kcol = qkv + (size_t)b * Tz * (3 * Cz) + Cz + h * HSz + sc;
  const bf16* vrow = Vt + ((size_t)bh * HSz + srow) * Tz + sc;
  const bf16* brow = bm + (size_t)(t0 + srow) * Tz + sc;
  // prefetch tile 0
  uint4 ka, kb, va, vb2, ba, bb2;
  {
    const bf16* kp = kcol + (size_t)srow * (3 * Cz);
    ka = *(const uint4*)kp;
    kb = *(const uint4*)(kp + 8);
    va = *(const uint4*)vrow;
    vb2 = *(const uint4*)(vrow + 8);
    ba = *(const uint4*)brow;
    bb2 = *(const uint4*)(brow + 8);
  }
  for (int kt = 0; kt < nk; kt++) {
    __syncthreads();  // all waves done reading previous tiles
    *(uint4*)&Ks[srow][sc] = ka;
    *(uint4*)&Ks[srow][sc + 8] = kb;
    *(uint4*)&Vs[srow][sc] = va;
    *(uint4*)&Vs[srow][sc + 8] = vb2;
    *(uint4*)&Bs[srow][sc] = ba;
    *(uint4*)&Bs[srow][sc + 8] = bb2;
    __syncthreads();  // tiles ready
    if (kt + 1 < nk) {
      int s1 = (kt + 1) * 64;
      const bf16* kp = kcol + (size_t)(s1 + srow) * (3 * Cz);
      ka = *(const uint4*)kp;
      kb = *(const uint4*)(kp + 8);
      const bf16* vp = vrow + s1;
      va = *(const uint4*)vp;
      vb2 = *(const uint4*)(vp + 8);
      const bf16* bp = brow + s1;
      ba = *(const uint4*)bp;
      bb2 = *(const uint4*)(bp + 8);
    }
    // ---- S = Q K^T
    f32x4 sacc[4] = {};
#pragma unroll
    for (int ks = 0; ks < 64; ks += 32) {
      bf16x8 aq = *(const bf16x8*)&Qs[w * 16 + ln][ks + q * 8];
#pragma unroll
      for (int j = 0; j < 4; j++) {
        bf16x8 bk = *(const bf16x8*)&Ks[j * 16 + ln][ks + q * 8];
        sacc[j] = MFMA16(aq, bk, sacc[j]);
      }
    }
    // ---- add fused bias/mask (LDS)
    float sval[4][4];
#pragma unroll
    for (int j = 0; j < 4; j++)
#pragma unroll
      for (int r = 0; r < 4; r++)
        sval[j][r] = fmaf(sacc[j][r], scale, bf2f(Bs[w * 16 + q * 4 + r][j * 16 + ln]));
    // ---- online softmax
    float rmax[4];
#pragma unroll
    for (int r = 0; r < 4; r++)
      rmax[r] = fmaxf(fmaxf(sval[0][r], sval[1][r]), fmaxf(sval[2][r], sval[3][r]));
#pragma unroll
    for (int msk = 8; msk >= 1; msk >>= 1)
#pragma unroll
      for (int r = 0; r < 4; r++)
        rmax[r] = fmaxf(rmax[r], __shfl_xor(rmax[r], msk));
    float nme[4], alpha[4];
#pragma unroll
    for (int r = 0; r < 4; r++) {
      float nm = fmaxf(mrow[r], rmax[r]);
      nme[r] = (nm < -1.0e37f) ? 0.0f : nm;  // fully-masked tile guard
      alpha[r] = __expf(mrow[r] - nm);       // exp(0)=1 vs lrow=0 is harmless
      mrow[r] = nm;
    }
    float pf[4][4];
    float psum[4] = {0.f, 0.f, 0.f, 0.f};
#pragma unroll
    for (int j = 0; j < 4; j++)
#pragma unroll
      for (int r = 0; r < 4; r++) {
        float p = __expf(sval[j][r] - nme[r]);
        pf[j][r] = p;
        psum[r] += p;
      }
#pragma unroll
    for (int msk = 8; msk >= 1; msk >>= 1)
#pragma unroll
      for (int r = 0; r < 4; r++) psum[r] += __shfl_xor(psum[r], msk);
#pragma unroll
    for (int r = 0; r < 4; r++) lrow[r] = alpha[r] * lrow[r] + psum[r];
#pragma unroll
    for (int jd = 0; jd < 4; jd++)
#pragma unroll
      for (int r = 0; r < 4; r++) Oacc[jd][r] *= alpha[r];
    // ---- P -> LDS (D-layout -> A-layout), wave-private
#pragma unroll
    for (int j = 0; j < 4; j++)
#pragma unroll
      for (int r = 0; r < 4; r++)
        Ps[w][q * 4 + r][j * 16 + ln] = f2bf(pf[j][r]);
    // ---- O += P V
#pragma unroll
    for (int ks = 0; ks < 64; ks += 32) {
      bf16x8 pa = *(const bf16x8*)&Ps[w][ln][ks + q * 8];
#pragma unroll
      for (int jd = 0; jd < 4; jd++) {
        bf16x8 vb = *(const bf16x8*)&Vs[jd * 16 + ln][ks + q * 8];
        Oacc[jd] = MFMA16(pa, vb, Oacc[jd]);
      }
    }
  }
#pragma unroll
  for (int r = 0; r < 4; r++) {
    float inv = 1.0f / lrow[r];
    int t_row = t_base + r;
#pragma unroll
    for (int jd = 0; jd < 4; jd++) {
      attn_out[(size_t)(b * Tz + t_row) * Cz + h * HSz + jd * 16 + ln] =
          f2bf(Oacc[jd][r] * inv);
    }
  }
}

// ---------------------------------------------------------------- launcher
extern "C" void kernel_launch(void* const* d_in, const int* in_sizes, int n_in,
                              void* d_out, int out_size, void* d_ws, size_t ws_size,
                              hipStream_t stream) {
  const int* idx = (const int*)d_in[0];
  int p0 = 7;
  if (n_in == 23) p0 = 6;
  else if (in_sizes[6] != Tz * Tz) p0 = 6;

  const void* r_tok_emb = d_in[1];
  const void* r_pe_w = d_in[2];
  const void* r_pe_b = d_in[3];
  const void* r_vlut = d_in[4];
  const void* r_rbias = d_in[5];
  const void* r_ln1_g = d_in[p0 + 0];
  const void* r_ln1_b = d_in[p0 + 1];
  const void* r_qw = d_in[p0 + 2];
  const void* r_kw = d_in[p0 + 3];
  const void* r_vw = d_in[p0 + 4];
  const void* r_proj_w = d_in[p0 + 5];
  const void* r_proj_b = d_in[p0 + 6];
  const void* r_ln2_g = d_in[p0 + 7];
  const void* r_ln2_b = d_in[p0 + 8];
  const void* r_ff1_w = d_in[p0 + 9];
  const void* r_ff1_b = d_in[p0 + 10];
  const void* r_ff2_w = d_in[p0 + 11];
  const void* r_ff2_b = d_in[p0 + 12];
  const void* r_lnf_g = d_in[p0 + 13];
  const void* r_lnf_b = d_in[p0 + 14];
  const void* r_head_w = d_in[p0 + 15];
  const void* r_head_b = d_in[p0 + 16];

  char* wsp = (char*)d_ws;
  auto alloc = [&](size_t bytes) {
    char* p = wsp;
    wsp += (bytes + 255) & ~(size_t)255;
    return (void*)p;
  };
  int* flag = (int*)alloc(256);
  float* x_res = (float*)alloc((size_t)NTOK * Cz * 4);
  bf16* h = (bf16*)alloc((size_t)NTOK * Cz * 2);
  bf16* qkv = (bf16*)alloc((size_t)NTOK * 3 * Cz * 2);
  bf16* attn = (bf16*)alloc((size_t)NTOK * Cz * 2);
  bf16* ffm = (bf16*)alloc((size_t)NTOK * 4 * Cz * 2);
  bf16* Vt = (bf16*)alloc((size_t)Bz * NHz * HSz * Tz * 2);
  bf16* wqkv_t = (bf16*)alloc((size_t)NLz * 3 * Cz * Cz * 2);
  bf16* proj_t = (bf16*)alloc((size_t)NLz * Cz * Cz * 2);
  bf16* ff1_t = (bf16*)alloc((size_t)NLz * 4 * Cz * Cz * 2);
  bf16* ff2_t = (bf16*)alloc((size_t)NLz * 4 * Cz * Cz * 2);
  bf16* head_t = (bf16*)alloc((size_t)VOCABz * Cz * 2);
  bf16* tok_emb = (bf16*)alloc((size_t)VOCABz * Cz * 2);
  bf16* pe_w = (bf16*)alloc(10 * Cz * 2);
  bf16* pe_b = (bf16*)alloc(Cz * 2);
  bf16* vlut = (bf16*)alloc(Tz * 10 * 2);
  bf16* rbias = (bf16*)alloc((size_t)Tz * Tz * 2);
  bf16* bmx = (bf16*)alloc((size_t)Tz * Tz * 2);
  bf16* ln1_g = (bf16*)alloc(NLz * Cz * 2);
  bf16* ln1_b = (bf16*)alloc(NLz * Cz * 2);
  bf16* proj_b = (bf16*)alloc(NLz * Cz * 2);
  bf16* ln2_g = (bf16*)alloc(NLz * Cz * 2);
  bf16* ln2_b = (bf16*)alloc(NLz * Cz * 2);
  bf16* ff1_b = (bf16*)alloc(NLz * 4 * Cz * 2);
  bf16* ff2_b = (bf16*)alloc(NLz * Cz * 2);
  bf16* lnf_g = (bf16*)alloc(Cz * 2);
  bf16* lnf_b = (bf16*)alloc(Cz * 2);
  bf16* head_b = (bf16*)alloc(VOCABz * 2);

  detect_kernel<<<1, 64, 0, stream>>>(r_ln1_g, flag);

  CPack cp;
  const void* csrc[NCONV] = {r_tok_emb, r_pe_w, r_pe_b, r_vlut, r_rbias,
                             r_ln1_g, r_ln1_b, r_proj_b, r_ln2_g, r_ln2_b,
                             r_ff1_b, r_ff2_b, r_lnf_g, r_lnf_b, r_head_b};
  bf16* cdst[NCONV] = {tok_emb, pe_w, pe_b, vlut, rbias,
                       ln1_g, ln1_b, proj_b, ln2_g, ln2_b,
                       ff1_b, ff2_b, lnf_g, lnf_b, head_b};
  int cn[NCONV] = {VOCABz * Cz, 10 * Cz, Cz, Tz * 10, Tz * Tz,
                   NLz * Cz, NLz * Cz, NLz * Cz, NLz * Cz, NLz * Cz,
                   NLz * 4 * Cz, NLz * Cz, Cz, Cz, VOCABz};
  for (int i = 0; i < NCONV; i++) { cp.s[i] = csrc[i]; cp.d[i] = cdst[i]; cp.n[i] = cn[i]; }
  convert_all<<<1024, 256, 0, stream>>>(cp, flag);
  build_bm<<<Tz * Tz / 256, 256, 0, stream>>>(rbias, bmx);

  for (int g = 0; g < 3; g++) {
    const void* src = (g == 0) ? r_qw : (g == 1) ? r_kw : r_vw;
    transpose_tiled<<<dim3(1, Cz / 64, NLz * NHz), 256, 0, stream>>>(
        src, wqkv_t, Cz, HSz, (size_t)Cz * HSz,
        (size_t)g * Cz * Cz, (size_t)3 * Cz * Cz, (size_t)HSz * Cz, NHz, flag);
  }
  transpose_tiled<<<dim3(Cz / 64, Cz / 64, NLz), 256, 0, stream>>>(
      r_proj_w, proj_t, Cz, Cz, (size_t)Cz * Cz, 0, (size_t)Cz * Cz, 0, 1, flag);
  transpose_tiled<<<dim3(4 * Cz / 64, Cz / 64, NLz), 256, 0, stream>>>(
      r_ff1_w, ff1_t, Cz, 4 * Cz, (size_t)4 * Cz * Cz, 0, (size_t)4 * Cz * Cz, 0, 1, flag);
  transpose_tiled<<<dim3(Cz / 64, 4 * Cz / 64, NLz), 256, 0, stream>>>(
      r_ff2_w, ff2_t, 4 * Cz, Cz, (size_t)4 * Cz * Cz, 0, (size_t)4 * Cz * Cz, 0, 1, flag);
  transpose_tiled<<<dim3(VOCABz / 64, Cz / 64, 1), 256, 0, stream>>>(
      r_head_w, head_t, Cz, VOCABz, 0, 0, 0, 0, 1, flag);

  embed_kernel<<<NTOK, 256, 0, stream>>>(idx, tok_emb, pe_w, pe_b, vlut, x_res);

  for (int l = 0; l < NLz; l++) {
    ln_kernel<<<NTOK / 4, 256, 0, stream>>>(x_res, ln1_g + l * Cz, ln1_b + l * Cz, h);
    gemm_mfma<4><<<dim3(3 * Cz / 128, NTOK / 128), 256, 0, stream>>>(
        h, wqkv_t + (size_t)l * 3 * Cz * Cz, nullptr, (float*)Vt, qkv,
        NTOK, 3 * Cz, Cz, 5, flag);
    attn_flash<<<dim3(Tz / 64, Bz * NHz), 256, 0, stream>>>(qkv, Vt, bmx, attn);
    gemm_mfma<2><<<dim3(Cz / 128, NTOK / 64), 256, 0, stream>>>(
        attn, proj_t + (size_t)l * Cz * Cz, proj_b + l * Cz, x_res, nullptr,
        NTOK, Cz, Cz, 2, flag);
    ln_kernel<<<NTOK / 4, 256, 0, stream>>>(x_res, ln2_g + l * Cz, ln2_b + l * Cz, h);
    gemm_mfma<4><<<dim3(4 * Cz / 128, NTOK / 128), 256, 0, stream>>>(
        h, ff1_t + (size_t)l * 4 * Cz * Cz, ff1_b + (size_t)l * 4 * Cz, nullptr,
        ffm, NTOK, 4 * Cz, Cz, 1, flag);
    gemm_mfma<2><<<dim3(Cz / 128, NTOK / 64), 256, 0, stream>>>(
        ffm, ff2_t + (size_t)l * 4 * Cz * Cz, ff2_b + l * Cz, x_res, nullptr,
        NTOK, Cz, 4 * Cz, 2, flag);
  }
  ln_kernel<<<NTOK / 4, 256, 0, stream>>>(x_res, lnf_g, lnf_b, h);
  gemm_mfma<2><<<dim3(VOCABz / 128, NTOK / 64), 256, 0, stream>>>(
      h, head_t, head_b, nullptr, d_out, NTOK, VOCABz, Cz, 3, flag);
}